// Round 2
// baseline (9187.556 us; speedup 1.0000x reference)
//
#include <hip/hip_runtime.h>

typedef unsigned int uint;
typedef unsigned short ushort;
typedef __attribute__((ext_vector_type(8))) short s16x8;
typedef __attribute__((ext_vector_type(4))) float f32x4;
typedef __attribute__((ext_vector_type(4))) uint u32x4;

// problem dims (fixed)
#define SEQ 1024
#define BATCH 64
#define INDIM 512
#define HID 1024

// ---- workspace layout (bytes) ----
#define OFF_BUF   0ull
#define SZ_BUF    (65536ull * 1024ull * 2ull)          // c0 / r0 / c1 (in-place), bf16
#define OFF_W0B   (OFF_BUF + SZ_BUF)                    // W_ih0 bf16 (1024x512)
#define OFF_WH0B  (OFF_W0B  + 1048576ull)               // W_hh0 bf16 (1024x1024)
#define OFF_W1B   (OFF_WH0B + 2097152ull)               // W_ih1 bf16
#define OFF_WH1B  (OFF_W1B  + 2097152ull)               // W_hh1 bf16
#define OFF_HINIT (OFF_WH1B + 2097152ull)               // hidden bf16 [2][64][1024]
#define OFF_HDBUF (OFF_HINIT + 262144ull)               // h double buffer [2][64][1024] bf16
#define OFF_CNT   (OFF_HDBUF + 262144ull)               // flags [2][4][1024] u32
#define OFF_PPART (OFF_CNT + 32768ull)                  // pooled partials [4][1024][1024] f32
#define WS_NEEDED (OFF_PPART + 16777216ull)

__device__ __forceinline__ ushort f2bf(float f) {
    uint u = __float_as_uint(f);
    uint r = (u + 0x7fffu + ((u >> 16) & 1u)) >> 16;
    return (ushort)r;
}
__device__ __forceinline__ float bf2f(ushort h) {
    return __uint_as_float(((uint)h) << 16);
}

// ---------------- prep: convert weights/hidden to bf16, zero flags ----------------
__global__ void k_prep(const float* Wih0, const float* Whh0, const float* Wih1,
                       const float* Whh1, const float* hid, char* ws) {
    ushort* w0  = (ushort*)(ws + OFF_W0B);
    ushort* wh0 = (ushort*)(ws + OFF_WH0B);
    ushort* w1  = (ushort*)(ws + OFF_W1B);
    ushort* wh1 = (ushort*)(ws + OFF_WH1B);
    ushort* hi  = (ushort*)(ws + OFF_HINIT);
    uint*   cnt = (uint*)(ws + OFF_CNT);
    const long long total = 524288 + 3 * 1048576 + 131072 + 8192;
    for (long long i = (long long)blockIdx.x * 256 + threadIdx.x; i < total;
         i += (long long)gridDim.x * 256) {
        long long j = i;
        if (j < 524288)  { w0[j]  = f2bf(Wih0[j]); continue; }  j -= 524288;
        if (j < 1048576) { wh0[j] = f2bf(Whh0[j]); continue; }  j -= 1048576;
        if (j < 1048576) { w1[j]  = f2bf(Wih1[j]); continue; }  j -= 1048576;
        if (j < 1048576) { wh1[j] = f2bf(Whh1[j]); continue; }  j -= 1048576;
        if (j < 131072)  { hi[j]  = f2bf(hid[j]);  continue; }  j -= 131072;
        cnt[j] = 0u;
    }
}

// ---------------- proj0: c0 = x @ W_ih0^T + b_ih0 + b_hh0 (bf16 out) ----------------
// grid 4096 x 256.  tile: M=64 (4 waves x 16 rows), N=256, K=512.
__launch_bounds__(256)
__global__ void k_proj0(const float* __restrict__ x, const float* __restrict__ bih,
                        const float* __restrict__ bhh, char* ws) {
    const ushort* W = (const ushort*)(ws + OFF_W0B);
    ushort* cbuf = (ushort*)(ws + OFF_BUF);
    int bx = blockIdx.x;
    int mtile = bx >> 2, ntile = bx & 3;
    int tid = threadIdx.x, w = tid >> 6, l = tid & 63;
    int lr = l & 15, lq = l >> 4;
    int arow = mtile * 64 + w * 16 + lr;

    f32x4 acc[16];
#pragma unroll
    for (int i = 0; i < 16; i++) acc[i] = (f32x4){0.f, 0.f, 0.f, 0.f};

    for (int kc = 0; kc < 16; kc++) {
        int k0 = kc * 32 + lq * 8;
        const f32x4* ap = (const f32x4*)(x + (long long)arow * 512 + k0);
        f32x4 a0 = ap[0], a1 = ap[1];
        s16x8 a;
        a[0] = (short)f2bf(a0[0]); a[1] = (short)f2bf(a0[1]);
        a[2] = (short)f2bf(a0[2]); a[3] = (short)f2bf(a0[3]);
        a[4] = (short)f2bf(a1[0]); a[5] = (short)f2bf(a1[1]);
        a[6] = (short)f2bf(a1[2]); a[7] = (short)f2bf(a1[3]);
#pragma unroll
        for (int nf = 0; nf < 16; nf++) {
            int col = ntile * 256 + nf * 16 + lr;
            s16x8 b = *(const s16x8*)(W + (long long)col * 512 + k0);
            acc[nf] = __builtin_amdgcn_mfma_f32_16x16x32_bf16(a, b, acc[nf], 0, 0, 0);
        }
    }
#pragma unroll
    for (int nf = 0; nf < 16; nf++) {
        int col = ntile * 256 + nf * 16 + lr;
        float bb = bih[col] + bhh[col];
#pragma unroll
        for (int j = 0; j < 4; j++) {
            int row = mtile * 64 + w * 16 + lq * 4 + j;
            cbuf[(long long)row * 1024 + col] = f2bf(acc[nf][j] + bb);
        }
    }
}

// ---------------- recurrence: h_t = tanh(c[t] + h_{t-1} @ Whh^T) ----------------
// grid 64 x 256.  4 batch-groups of 16; 16 WGs/group; WG owns 64 hidden cols.
// W slice register-resident (128 VGPR/lane). Per-step sync via monotone counters.
__launch_bounds__(256, 1)
__global__ void k_rec(char* ws, int layer, int pool) {
    const ushort* Whh = (const ushort*)(ws + (layer ? OFF_WH1B : OFF_WH0B));
    ushort* cbuf = (ushort*)(ws + OFF_BUF);
    ushort* hdb  = (ushort*)(ws + OFF_HDBUF);
    const ushort* hinit = (const ushort*)(ws + OFF_HINIT) + layer * 65536;
    uint* cnt = (uint*)(ws + OFF_CNT) + layer * 4096;
    float* ppart = (float*)(ws + OFF_PPART);

    int wg = blockIdx.x;
    int g = wg & 3, islice = wg >> 2;
    int wgcol = islice * 64;
    int tid = threadIdx.x, w = tid >> 6, l = tid & 63;
    int lr = l & 15, lq = l >> 4;
    int mycol = wgcol + w * 16 + lr;

    __shared__ __align__(16) char lds[32768];

    // preload W_hh slice: B-frag[kc]: B[k][col] = Whh[col][k]
    s16x8 wfrag[32];
#pragma unroll
    for (int kc = 0; kc < 32; kc++)
        wfrag[kc] = *(const s16x8*)(Whh + (long long)mycol * 1024 + kc * 32 + lq * 8);

    for (int t = 0; t < 1024; t++) {
        // prefetch c tile (independent of recurrence) before waiting
        int cbase = (t * 64 + g * 16) * 1024;
        ushort cf[4];
#pragma unroll
        for (int j = 0; j < 4; j++)
            cf[j] = cbuf[cbase + (lq * 4 + j) * 1024 + mycol];

        if (t > 0) {
            if (tid == 0) {
                uint* f = &cnt[g * 1024 + (t - 1)];
                while (__hip_atomic_load(f, __ATOMIC_RELAXED, __HIP_MEMORY_SCOPE_AGENT) < 16u)
                    __builtin_amdgcn_s_sleep(1);
                (void)__hip_atomic_load(f, __ATOMIC_ACQUIRE, __HIP_MEMORY_SCOPE_AGENT);
            }
            __syncthreads();
        }

        // cooperative load of h_{t-1} (16 rows x 1024 bf16 = 32 KB) into swizzled LDS
        const ushort* hsrc = (t == 0) ? (hinit + g * 16 * 1024)
                                      : (hdb + ((t - 1) & 1) * 65536 + g * 16 * 1024);
#pragma unroll
        for (int i = 0; i < 8; i++) {
            int off = tid * 16 + i * 4096;
            u32x4 v = *(const u32x4*)((const char*)hsrc + off);
            int row = off >> 11;
            int sw = (off & 2047) ^ ((row & 7) << 4);
            *(u32x4*)(lds + row * 2048 + sw) = v;
        }
        __syncthreads();

        f32x4 acc = (f32x4){0.f, 0.f, 0.f, 0.f};
#pragma unroll
        for (int kc = 0; kc < 32; kc++) {
            int boff = (kc * 64 + lq * 16) ^ ((lr & 7) << 4);
            s16x8 a = *(const s16x8*)(lds + lr * 2048 + boff);
            acc = __builtin_amdgcn_mfma_f32_16x16x32_bf16(a, wfrag[kc], acc, 0, 0, 0);
        }

        float hn[4];
#pragma unroll
        for (int j = 0; j < 4; j++) {
            float z = acc[j] + bf2f(cf[j]);
            z = fminf(fmaxf(z, -30.f), 30.f);
            float e = __expf(2.f * z);
            hn[j] = (e - 1.f) / (e + 1.f);
        }

        ushort* hdst = hdb + (t & 1) * 65536 + g * 16 * 1024;
#pragma unroll
        for (int j = 0; j < 4; j++)
            hdst[(lq * 4 + j) * 1024 + mycol] = f2bf(hn[j]);

        if (!pool) {
            // layer 0: write r0[t] in place over c0[t]
#pragma unroll
            for (int j = 0; j < 4; j++)
                cbuf[cbase + (lq * 4 + j) * 1024 + mycol] = f2bf(hn[j]);
        } else {
            // layer 1: accumulate batch-sum for pooling
            float s = hn[0] + hn[1] + hn[2] + hn[3];
            s += __shfl_xor(s, 16);
            s += __shfl_xor(s, 32);
            if (l < 16) ppart[(g * 1024 + t) * 1024 + mycol] = s;
        }

        __syncthreads();  // drains vmcnt: all waves' stores are in L2 before release
        if (tid == 0)
            __hip_atomic_fetch_add(&cnt[g * 1024 + t], 1u, __ATOMIC_RELEASE,
                                   __HIP_MEMORY_SCOPE_AGENT);
    }
}

// ---------------- proj1 (IN-PLACE): c1 = r0 @ W_ih1^T + b_ih1 + b_hh1 ----------------
// grid 2048 x 256. Stage 32 full rows in LDS, then overwrite. K=1024, N=1024.
__launch_bounds__(256, 1)
__global__ void k_proj1(const float* __restrict__ bih, const float* __restrict__ bhh,
                        char* ws) {
    const ushort* W = (const ushort*)(ws + OFF_W1B);
    ushort* buf = (ushort*)(ws + OFF_BUF);
    int bx = blockIdx.x;
    long long R = (long long)bx * 32;
    int tid = threadIdx.x, w = tid >> 6, l = tid & 63;
    int lr = l & 15, lq = l >> 4;

    __shared__ __align__(16) char lds[65536];
#pragma unroll
    for (int i = 0; i < 16; i++) {
        int off = tid * 16 + i * 4096;
        u32x4 v = *(const u32x4*)((const char*)(buf + R * 1024) + off);
        int row = off >> 11;
        int sw = (off & 2047) ^ ((row & 7) << 4);
        *(u32x4*)(lds + row * 2048 + sw) = v;
    }
    __syncthreads();

    f32x4 acc[2][16];
#pragma unroll
    for (int m = 0; m < 2; m++)
#pragma unroll
        for (int i = 0; i < 16; i++) acc[m][i] = (f32x4){0.f, 0.f, 0.f, 0.f};

    for (int kc = 0; kc < 32; kc++) {
        int boff = kc * 64 + lq * 16;
        int r0 = lr, r1 = 16 + lr;
        s16x8 a0 = *(const s16x8*)(lds + r0 * 2048 + (boff ^ ((r0 & 7) << 4)));
        s16x8 a1 = *(const s16x8*)(lds + r1 * 2048 + (boff ^ ((r1 & 7) << 4)));
#pragma unroll
        for (int nf = 0; nf < 16; nf++) {
            int col = w * 256 + nf * 16 + lr;
            s16x8 b = *(const s16x8*)(W + (long long)col * 1024 + kc * 32 + lq * 8);
            acc[0][nf] = __builtin_amdgcn_mfma_f32_16x16x32_bf16(a0, b, acc[0][nf], 0, 0, 0);
            acc[1][nf] = __builtin_amdgcn_mfma_f32_16x16x32_bf16(a1, b, acc[1][nf], 0, 0, 0);
        }
    }
#pragma unroll
    for (int nf = 0; nf < 16; nf++) {
        int col = w * 256 + nf * 16 + lr;
        float bb = bih[col] + bhh[col];
#pragma unroll
        for (int mf = 0; mf < 2; mf++)
#pragma unroll
            for (int j = 0; j < 4; j++)
                buf[(R + mf * 16 + lq * 4 + j) * 1024 + col] = f2bf(acc[mf][nf][j] + bb);
    }
}

// ---------------- head: pooled mean -> FC1+ReLU -> FC2+sigmoid ----------------
// grid 128 x 256; each WG handles 8 sequence positions.
__launch_bounds__(256)
__global__ void k_head(const float* __restrict__ W1, const float* __restrict__ b1,
                       const float* __restrict__ W2, const float* __restrict__ b2,
                       char* ws, float* __restrict__ out) {
    const float* pp = (const float*)(ws + OFF_PPART);
    int bx = blockIdx.x;
    int t0 = bx * 8;
    int tid = threadIdx.x;

    __shared__ float pl[8][1024];
    __shared__ float red[256][8];

    for (int i = tid; i < 8192; i += 256) {
        int tt = i >> 10, k = i & 1023;
        int base = (t0 + tt) * 1024 + k;
        float s = pp[base] + pp[1048576 + base] + pp[2097152 + base] + pp[3145728 + base];
        pl[tt][k] = s * (1.f / 64.f);
    }
    __syncthreads();

    float po[8];
#pragma unroll
    for (int tt = 0; tt < 8; tt++) po[tt] = 0.f;

    for (int jj = 0; jj < 2; jj++) {
        int j = tid + jj * 256;
        float accv[8];
        float bias = b1[j];
#pragma unroll
        for (int tt = 0; tt < 8; tt++) accv[tt] = bias;
        const float* wr = W1 + (long long)j * 1024;
        for (int k = 0; k < 1024; k += 8) {
            f32x4 wa = *(const f32x4*)(wr + k);
            f32x4 wb = *(const f32x4*)(wr + k + 4);
#pragma unroll
            for (int tt = 0; tt < 8; tt++) {
                accv[tt] += pl[tt][k] * wa[0] + pl[tt][k + 1] * wa[1] +
                            pl[tt][k + 2] * wa[2] + pl[tt][k + 3] * wa[3] +
                            pl[tt][k + 4] * wb[0] + pl[tt][k + 5] * wb[1] +
                            pl[tt][k + 6] * wb[2] + pl[tt][k + 7] * wb[3];
            }
        }
        float w2 = W2[j];
#pragma unroll
        for (int tt = 0; tt < 8; tt++) po[tt] += fmaxf(accv[tt], 0.f) * w2;
    }

#pragma unroll
    for (int tt = 0; tt < 8; tt++) red[tid][tt] = po[tt];
    __syncthreads();
    for (int st = 128; st >= 1; st >>= 1) {
        if (tid < st) {
#pragma unroll
            for (int tt = 0; tt < 8; tt++) red[tid][tt] += red[tid + st][tt];
        }
        __syncthreads();
    }
    if (tid < 8) out[t0 + tid] = 1.f / (1.f + __expf(-(red[0][tid] + b2[0])));
}

extern "C" void kernel_launch(void* const* d_in, const int* in_sizes, int n_in,
                              void* d_out, int out_size, void* d_ws, size_t ws_size,
                              hipStream_t stream) {
    const float* x    = (const float*)d_in[0];
    const float* hid  = (const float*)d_in[1];
    const float* Wih0 = (const float*)d_in[2];
    const float* Whh0 = (const float*)d_in[3];
    const float* bih0 = (const float*)d_in[4];
    const float* bhh0 = (const float*)d_in[5];
    const float* Wih1 = (const float*)d_in[6];
    const float* Whh1 = (const float*)d_in[7];
    const float* bih1 = (const float*)d_in[8];
    const float* bhh1 = (const float*)d_in[9];
    const float* W1   = (const float*)d_in[10];
    const float* b1   = (const float*)d_in[11];
    const float* W2   = (const float*)d_in[12];
    const float* b2   = (const float*)d_in[13];
    char* ws = (char*)d_ws;
    float* out = (float*)d_out;

    hipLaunchKernelGGL(k_prep, dim3(1024), dim3(256), 0, stream,
                       Wih0, Whh0, Wih1, Whh1, hid, ws);
    hipLaunchKernelGGL(k_proj0, dim3(4096), dim3(256), 0, stream, x, bih0, bhh0, ws);
    hipLaunchKernelGGL(k_rec, dim3(64), dim3(256), 0, stream, ws, 0, 0);
    hipLaunchKernelGGL(k_proj1, dim3(2048), dim3(256), 0, stream, bih1, bhh1, ws);
    hipLaunchKernelGGL(k_rec, dim3(64), dim3(256), 0, stream, ws, 1, 1);
    hipLaunchKernelGGL(k_head, dim3(128), dim3(256), 0, stream, W1, b1, W2, b2, ws, out);
}